// Round 2
// baseline (427.658 us; speedup 1.0000x reference)
//
#include <hip/hip_runtime.h>

#define HIDDEN 1024
#define INTER  704
#define NEXP   32
#define TM     128

typedef __attribute__((ext_vector_type(8))) short bf16x8;
typedef __attribute__((ext_vector_type(4))) float f32x4;

__device__ __forceinline__ unsigned short f2bf(float f) {
    union { float f; unsigned u; } v; v.f = f;
    unsigned r = v.u + 0x7FFF + ((v.u >> 16) & 1);   // RNE
    return (unsigned short)(r >> 16);
}
__device__ __forceinline__ unsigned pkbf(float lo, float hi) {
    return (unsigned)f2bf(lo) | ((unsigned)f2bf(hi) << 16);
}
__device__ __forceinline__ float fcomp(const float4& v, int c) {
    return c == 0 ? v.x : c == 1 ? v.y : c == 2 ? v.z : v.w;
}

__device__ __forceinline__ void load_lds16(const void* g, void* l) {
    __builtin_amdgcn_global_load_lds(
        (const __attribute__((address_space(1))) void*)g,
        (__attribute__((address_space(3))) void*)l, 16, 0, 0);
}

__device__ __forceinline__ unsigned lds_addr(const void* p) {
    return (unsigned)(size_t)(const __attribute__((address_space(3))) void*)p;
}

// asm LDS ops: invisible to the memory legalizer, so no vmcnt(0) drain is
// inserted against outstanding global_load_lds DMAs (that drain was the
// entire round-1 stall). Waits are controlled manually per rule #18.
__device__ __forceinline__ bf16x8 dsr128(unsigned addr, int off) {
    bf16x8 r;
    asm volatile("ds_read_b128 %0, %1 offset:%2" : "=v"(r) : "v"(addr), "i"(off));
    return r;
}
__device__ __forceinline__ void dsw32(unsigned addr, unsigned val, int off) {
    asm volatile("ds_write_b32 %0, %1 offset:%2" :: "v"(addr), "v"(val), "i"(off));
}

#define MEMFENCE asm volatile("" ::: "memory")
#define PIPE_BARRIER(VM) do { \
    asm volatile("s_waitcnt vmcnt(" VM ") lgkmcnt(0)" ::: "memory"); \
    __builtin_amdgcn_s_barrier(); } while (0)

// map block m-index -> (expert, global row0, valid rows) over ragged groups
__device__ __forceinline__ bool map_tile(const int* s_tpe, int bm,
                                         int& row0, int& rows, int& e) {
    int start = 0, rem = bm;
    for (int i = 0; i < NEXP; ++i) {
        int g = s_tpe[i];
        int nt = (g + TM - 1) / TM;
        if (rem < nt) { row0 = start + rem * TM; rows = min(TM, g - rem * TM); e = i; return true; }
        rem -= nt; start += g;
    }
    return false;
}

// ---------------- prep: x fp32 -> bf16 (same layout) ----------------
__global__ void cvt_x(const float* __restrict__ x, unsigned short* __restrict__ xb, int n4) {
    int i = blockIdx.x * blockDim.x + threadIdx.x;
    for (; i < n4; i += gridDim.x * blockDim.x) {
        float4 v = ((const float4*)x)[i];
        uint2 o;
        o.x = pkbf(v.x, v.y);
        o.y = pkbf(v.z, v.w);
        ((uint2*)xb)[i] = o;
    }
}

// ---------------- GEMM1 + SwiGLU: h = silu(x@w1) * (x@w3) ----------------
__global__ __launch_bounds__(256, 3)
void gemm1_swiglu(const unsigned short* __restrict__ xb, const int* __restrict__ tpe,
                  const float* __restrict__ w1w3, unsigned short* __restrict__ h)
{
    __shared__ int s_tpe[NEXP];
    __shared__ __align__(16) unsigned short sA[3][128 * 32];  // ring, 8192 B/slot
    __shared__ __align__(16) unsigned short sB[2][128 * 32];  // ping-pong

    int t = threadIdx.x;
    if (t < NEXP) s_tpe[t] = tpe[t];
    __syncthreads();

    int row0, rows, e;
    if (!map_tile(s_tpe, blockIdx.x, row0, rows, e)) return;
    int jb = blockIdx.y;   // 0..10

    int wv = t >> 6, lane = t & 63, l16 = lane & 15, quad = lane >> 4;
    int wr = wv >> 1, wc = wv & 1;

    int srow = lane >> 2, sblk = lane & 3;
    int gblk = sblk ^ (srow & 3);
    int bs = t & 1, bg = (t >> 1) & 7, kq = t >> 4;   // kq 0..15
    int xk = l16 & 3;

    const unsigned short* abase = xb + (size_t)row0 * HIDDEN;
    const float* bbase = w1w3 + (size_t)e * HIDDEN * 1408 + bs * 704 + jb * 64 + bg * 8;

    unsigned sA0 = lds_addr(&sA[0][0]);
    unsigned sB0 = lds_addr(&sB[0][0]);

    // fragment read offsets (bytes)
    int hh = l16 >> 3;
    unsigned aoff  = (unsigned)((wr * 64 + l16) * 64 + ((quad ^ xk) << 4));
    unsigned boffE = (unsigned)((wc * 64 + l16) * 64 + ((quad ^ hh) << 4));
    unsigned boffO = (unsigned)((wc * 64 + 16 + l16) * 64 + ((quad ^ ((2 + hh) & 3)) << 4));
    // B staging write bases (bytes): c = 16*bg + 2*j + bs, key = (2*bg + (j>>2)) & 3
    unsigned wLo = (unsigned)((16 * bg + bs) * 64 + ((kq & 3) << 2) + (((kq >> 2) ^ ((2 * bg) & 3)) << 4));
    unsigned wHi = (unsigned)((16 * bg + bs) * 64 + ((kq & 3) << 2) + (((kq >> 2) ^ ((2 * bg + 1) & 3)) << 4));

    f32x4 acc[4][4];
    #pragma unroll
    for (int i = 0; i < 4; i++)
        #pragma unroll
        for (int j = 0; j < 4; j++) acc[i][j] = (f32x4)(0.f);

    auto loadB = [&](int ko, float4 (&bv)[4]) {
        const float* p = bbase + (size_t)(ko + 2 * kq) * 1408;
        bv[0] = *(const float4*)(p);
        bv[1] = *(const float4*)(p + 4);
        bv[2] = *(const float4*)(p + 1408);
        bv[3] = *(const float4*)(p + 1408 + 4);
    };
    auto stageA = [&](unsigned short* dst, int ko) {
        #pragma unroll
        for (int i = 0; i < 2; ++i) {
            int r = wv * 32 + i * 16 + srow;
            if (r < rows)
                load_lds16(abase + (size_t)r * HIDDEN + ko + gblk * 8,
                           dst + (wv * 32 + i * 16) * 32);
        }
    };
    auto writeB = [&](unsigned bufAddr, const float4 (&bv)[4]) {
        unsigned aLo = bufAddr + wLo, aHi = bufAddr + wHi;
        #pragma unroll
        for (int j = 0; j < 4; ++j)
            dsw32(aLo, pkbf(fcomp(bv[0], j), fcomp(bv[2], j)), 128 * j);
        #pragma unroll
        for (int j = 4; j < 8; ++j)
            dsw32(aHi, pkbf(fcomp(bv[1], j - 4), fcomp(bv[3], j - 4)), 128 * j);
    };
    auto compute = [&](unsigned aBuf, unsigned bBuf) {
        bf16x8 a[4], b[4];
        unsigned aA = aBuf + aoff, bE = bBuf + boffE, bO = bBuf + boffO;
        a[0] = dsr128(aA, 0);    a[1] = dsr128(aA, 1024);
        a[2] = dsr128(aA, 2048); a[3] = dsr128(aA, 3072);
        b[0] = dsr128(bE, 0);    b[2] = dsr128(bE, 2048);
        b[1] = dsr128(bO, 0);    b[3] = dsr128(bO, 2048);
        asm volatile("s_waitcnt lgkmcnt(0)" ::: "memory");
        __builtin_amdgcn_sched_barrier(0);
        #pragma unroll
        for (int rt = 0; rt < 4; ++rt)
            #pragma unroll
            for (int ct = 0; ct < 4; ++ct)
                acc[rt][ct] = __builtin_amdgcn_mfma_f32_16x16x32_bf16(a[rt], b[ct], acc[rt][ct], 0, 0, 0);
    };

    const int NK = HIDDEN / 32;   // 32 chunks
    float4 bv0[4], bv1[4];

    // prologue: chunk0 -> sA[0]+sB[0]; chunk1 -> sA[1] (DMA) + bv1 (regs)
    stageA(&sA[0][0], 0);
    MEMFENCE;
    loadB(0, bv0);
    MEMFENCE;
    stageA(&sA[1][0], 32);
    MEMFENCE;
    loadB(32, bv1);
    MEMFENCE;
    writeB(sB0, bv0);
    PIPE_BARRIER("6");

    int rd = 0, bufB = 0;
    for (int b = 1; b <= NK - 2; b += 2) {   // bodies 1..30
        int st = rd + 2; if (st >= 3) st -= 3;
        stageA(&sA[st][0], (b + 1) * 32);
        MEMFENCE;
        loadB((b + 1) * 32, bv0);
        MEMFENCE;
        compute(sA0 + (unsigned)rd * 8192u, sB0 + (unsigned)bufB * 8192u);
        writeB(sB0 + (unsigned)(bufB ^ 1) * 8192u, bv1);
        PIPE_BARRIER("6");
        rd = rd + 1; if (rd >= 3) rd -= 3;
        bufB ^= 1;

        st = rd + 2; if (st >= 3) st -= 3;
        stageA(&sA[st][0], (b + 2) * 32);
        MEMFENCE;
        loadB((b + 2) * 32, bv1);
        MEMFENCE;
        compute(sA0 + (unsigned)rd * 8192u, sB0 + (unsigned)bufB * 8192u);
        writeB(sB0 + (unsigned)(bufB ^ 1) * 8192u, bv0);
        PIPE_BARRIER("6");
        rd = rd + 1; if (rd >= 3) rd -= 3;
        bufB ^= 1;
    }
    // tail body 31: compute chunk 30, stage B chunk 31
    compute(sA0 + (unsigned)rd * 8192u, sB0 + (unsigned)bufB * 8192u);
    writeB(sB0 + (unsigned)(bufB ^ 1) * 8192u, bv1);
    PIPE_BARRIER("0");
    rd = rd + 1; if (rd >= 3) rd -= 3;
    bufB ^= 1;
    compute(sA0 + (unsigned)rd * 8192u, sB0 + (unsigned)bufB * 8192u);   // chunk 31

    // ---- epilogue: SwiGLU via shfl_xor(1), store h bf16 ----
    #pragma unroll
    for (int rt = 0; rt < 4; ++rt) {
        #pragma unroll
        for (int reg = 0; reg < 4; ++reg) {
            int rl = wr * 64 + rt * 16 + quad * 4 + reg;
            bool ok = rl < rows;
            size_t grow = (size_t)(row0 + rl);
            #pragma unroll
            for (int ct = 0; ct < 4; ++ct) {
                float own = acc[rt][ct][reg];
                float oth = __shfl_xor(own, 1, 64);
                float g = (l16 & 1) ? oth : own;
                float u = (l16 & 1) ? own : oth;
                float sv = g / (1.f + __expf(-g)) * u;
                if (ok && !(l16 & 1)) {
                    int c = jb * 64 + ((wc * 64 + ct * 16 + l16) >> 1);
                    h[grow * INTER + c] = f2bf(sv);
                }
            }
        }
    }
}

// ---------------- GEMM2: out = h @ w2 ----------------
__global__ __launch_bounds__(256, 3)
void gemm2(const unsigned short* __restrict__ h, const int* __restrict__ tpe,
           const float* __restrict__ w2, float* __restrict__ out)
{
    __shared__ int s_tpe[NEXP];
    __shared__ __align__(16) unsigned short sA[3][128 * 32];
    __shared__ __align__(16) unsigned short sB[2][128 * 32];

    int t = threadIdx.x;
    if (t < NEXP) s_tpe[t] = tpe[t];
    __syncthreads();

    int row0, rows, e;
    if (!map_tile(s_tpe, blockIdx.x, row0, rows, e)) return;
    int nb = blockIdx.y;   // 0..7

    int wv = t >> 6, lane = t & 63, l16 = lane & 15, quad = lane >> 4;
    int wr = wv >> 1, wc = wv & 1;
    int srow = lane >> 2, sblk = lane & 3;
    int gblk = sblk ^ (srow & 3);
    int bg = t & 15, kq = t >> 4;   // 16 col-groups x 8 cols
    int xk = l16 & 3;

    const unsigned short* abase = h + (size_t)row0 * INTER;
    const float* bbase = w2 + (size_t)e * INTER * HIDDEN + nb * 128 + bg * 8;

    unsigned sA0 = lds_addr(&sA[0][0]);
    unsigned sB0 = lds_addr(&sB[0][0]);

    int hh = l16 >> 3;
    unsigned aoff  = (unsigned)((wr * 64 + l16) * 64 + ((quad ^ xk) << 4));
    unsigned boffE = (unsigned)((wc * 64 + l16) * 64 + ((quad ^ hh) << 4));
    unsigned boffO = (unsigned)((wc * 64 + 16 + l16) * 64 + ((quad ^ ((2 + hh) & 3)) << 4));
    // B staging write base: c = 8*bg + j, key = bg & 3 (j<8)
    unsigned wB = (unsigned)(512 * bg + ((kq & 3) << 2) + (((kq >> 2) ^ (bg & 3)) << 4));

    f32x4 acc[4][4];
    #pragma unroll
    for (int i = 0; i < 4; i++)
        #pragma unroll
        for (int j = 0; j < 4; j++) acc[i][j] = (f32x4)(0.f);

    auto loadB = [&](int ko, float4 (&bv)[4]) {
        const float* p = bbase + (size_t)(ko + 2 * kq) * HIDDEN;
        bv[0] = *(const float4*)(p);
        bv[1] = *(const float4*)(p + 4);
        bv[2] = *(const float4*)(p + HIDDEN);
        bv[3] = *(const float4*)(p + HIDDEN + 4);
    };
    auto stageA = [&](unsigned short* dst, int ko) {
        #pragma unroll
        for (int i = 0; i < 2; ++i) {
            int r = wv * 32 + i * 16 + srow;
            if (r < rows)
                load_lds16(abase + (size_t)r * INTER + ko + gblk * 8,
                           dst + (wv * 32 + i * 16) * 32);
        }
    };
    auto writeB = [&](unsigned bufAddr, const float4 (&bv)[4]) {
        unsigned ad = bufAddr + wB;
        #pragma unroll
        for (int j = 0; j < 4; ++j)
            dsw32(ad, pkbf(fcomp(bv[0], j), fcomp(bv[2], j)), 64 * j);
        #pragma unroll
        for (int j = 4; j < 8; ++j)
            dsw32(ad, pkbf(fcomp(bv[1], j - 4), fcomp(bv[3], j - 4)), 64 * j);
    };
    auto compute = [&](unsigned aBuf, unsigned bBuf) {
        bf16x8 a[4], b[4];
        unsigned aA = aBuf + aoff, bE = bBuf + boffE, bO = bBuf + boffO;
        a[0] = dsr128(aA, 0);    a[1] = dsr128(aA, 1024);
        a[2] = dsr128(aA, 2048); a[3] = dsr128(aA, 3072);
        b[0] = dsr128(bE, 0);    b[2] = dsr128(bE, 2048);
        b[1] = dsr128(bO, 0);    b[3] = dsr128(bO, 2048);
        asm volatile("s_waitcnt lgkmcnt(0)" ::: "memory");
        __builtin_amdgcn_sched_barrier(0);
        #pragma unroll
        for (int rt = 0; rt < 4; ++rt)
            #pragma unroll
            for (int ct = 0; ct < 4; ++ct)
                acc[rt][ct] = __builtin_amdgcn_mfma_f32_16x16x32_bf16(a[rt], b[ct], acc[rt][ct], 0, 0, 0);
    };

    const int NK = INTER / 32;   // 22 chunks
    float4 bv0[4], bv1[4];

    stageA(&sA[0][0], 0);
    MEMFENCE;
    loadB(0, bv0);
    MEMFENCE;
    stageA(&sA[1][0], 32);
    MEMFENCE;
    loadB(32, bv1);
    MEMFENCE;
    writeB(sB0, bv0);
    PIPE_BARRIER("6");

    int rd = 0, bufB = 0;
    for (int b = 1; b <= NK - 2; b += 2) {   // bodies 1..20
        int st = rd + 2; if (st >= 3) st -= 3;
        stageA(&sA[st][0], (b + 1) * 32);
        MEMFENCE;
        loadB((b + 1) * 32, bv0);
        MEMFENCE;
        compute(sA0 + (unsigned)rd * 8192u, sB0 + (unsigned)bufB * 8192u);
        writeB(sB0 + (unsigned)(bufB ^ 1) * 8192u, bv1);
        PIPE_BARRIER("6");
        rd = rd + 1; if (rd >= 3) rd -= 3;
        bufB ^= 1;

        st = rd + 2; if (st >= 3) st -= 3;
        stageA(&sA[st][0], (b + 2) * 32);
        MEMFENCE;
        loadB((b + 2) * 32, bv1);
        MEMFENCE;
        compute(sA0 + (unsigned)rd * 8192u, sB0 + (unsigned)bufB * 8192u);
        writeB(sB0 + (unsigned)(bufB ^ 1) * 8192u, bv0);
        PIPE_BARRIER("6");
        rd = rd + 1; if (rd >= 3) rd -= 3;
        bufB ^= 1;
    }
    compute(sA0 + (unsigned)rd * 8192u, sB0 + (unsigned)bufB * 8192u);
    writeB(sB0 + (unsigned)(bufB ^ 1) * 8192u, bv1);
    PIPE_BARRIER("0");
    rd = rd + 1; if (rd >= 3) rd -= 3;
    bufB ^= 1;
    compute(sA0 + (unsigned)rd * 8192u, sB0 + (unsigned)bufB * 8192u);

    #pragma unroll
    for (int rt = 0; rt < 4; ++rt) {
        #pragma unroll
        for (int reg = 0; reg < 4; ++reg) {
            int rl = wr * 64 + rt * 16 + quad * 4 + reg;
            if (rl < rows) {
                size_t grow = (size_t)(row0 + rl);
                #pragma unroll
                for (int ct = 0; ct < 4; ++ct)
                    out[grow * HIDDEN + nb * 128 + wc * 64 + ct * 16 + l16] = acc[rt][ct][reg];
            }
        }
    }
}

extern "C" void kernel_launch(void* const* d_in, const int* in_sizes, int n_in,
                              void* d_out, int out_size, void* d_ws, size_t ws_size,
                              hipStream_t stream) {
    const float* x    = (const float*)d_in[0];
    const int*   tpe  = (const int*)d_in[1];
    const float* w1w3 = (const float*)d_in[2];
    const float* w2   = (const float*)d_in[3];
    float* out = (float*)d_out;

    // ws (bf16 elems): h [8192*704] | xb [8192*1024]  (~27.5 MB)
    unsigned short* h  = (unsigned short*)d_ws;
    unsigned short* xb = h + (size_t)8192 * INTER;

    hipLaunchKernelGGL(cvt_x, dim3(1024), dim3(256), 0, stream, x, xb, 8192 * HIDDEN / 4);
    hipLaunchKernelGGL(gemm1_swiglu, dim3(96, 11), dim3(256), 0, stream, xb, tpe, w1w3, h);
    hipLaunchKernelGGL(gemm2, dim3(96, 8), dim3(256), 0, stream, h, tpe, w2, out);
}